// Round 9
// baseline (4484.363 us; speedup 1.0000x reference)
//
#include <hip/hip_runtime.h>
#include <hip/hip_bf16.h>

// ============================================================================
// TCN fp32, V5. Same bit-exact arithmetic as the passing V4/V2 (per-output
// residue-sweep order ((P3+P2)+P1)+P0, epilogue expressions verbatim, head
// verbatim), re-tiled for arithmetic intensity:
//   512 thr = 32 CG(8 co) x 16 TG(4 t)  -> 32 outputs/thread
//   per ci-iter: 96 FMAs per {2 ds_read_b128 + 6 global float4 wv loads}
//   (V4 was 48 FMAs per {2 + 3} with only 16 outputs/thread -> 2x VALU
//    instruction inflation per rocprof: VALUBusy-time 2.07x the FMA floor)
// Weights pre-transposed in d_ws (ws path PROVEN taken in rounds 5/7 ->
// ws_size >= 2.5 MB; V2 fallback dropped). LDS: 64 KB bufH + 9.2 KB xs.
// __launch_bounds__(512,4): VGPR<=128, 2 blocks/CU, 16 waves.
// `processed` written as FLOAT values; postproc decides from logits directly.
// ============================================================================

#define T_LEN 4096
#define CIN   34
#define EPSV  1e-5f
#define HALO  16
#define TT    48
#define TW    64
#define NTILE 86   // ceil(4096/48)

// ws float offsets
#define WOFF_WT1 0        // [102][256]
#define WOFF_WT2 26112    // [768][256]
#define WOFF_WT3 222720
#define WOFF_WT4 419328
#define WOFF_WTD 615936   // [34][256]
#define WS_FLOATS 624640  // 2,498,560 bytes

__device__ __forceinline__ int hswz(int row, int col) {
    return row * TW + ((((col >> 2) ^ ((row >> 3) & 15)) << 2) | (col & 3));
}
__device__ __forceinline__ float4* lds_ptr4(float* buf, int row, int col) {
    return (float4*)&buf[row * TW + (((col >> 2) ^ ((row >> 3) & 15)) << 2)];
}
__device__ __forceinline__ float4 lds_read4(const float* buf, int row, int col) {
    return *(const float4*)&buf[row * TW + (((col >> 2) ^ ((row >> 3) & 15)) << 2)];
}

// ===========================================================================
// prep: transpose weights into ws.  WT[r=ci*3+k][co]; WTD[ci][co].
// ===========================================================================
__global__ __launch_bounds__(256) void prep_v3(
    const float* __restrict__ c0w1, const float* __restrict__ c0w2,
    const float* __restrict__ c1w1, const float* __restrict__ c1w2,
    const float* __restrict__ c0dw, float* __restrict__ ws)
{
    int idx = blockIdx.x * 256 + threadIdx.x;
    if (idx < 26112) {
        int co = idx & 255, r = idx >> 8, ci = r / 3, kk = r % 3;
        ws[WOFF_WT1 + idx] = c0w1[(co * CIN + ci) * 3 + kk];
        return;
    }
    idx -= 26112;
    if (idx < 196608) {
        int co = idx & 255, r = idx >> 8, ci = r / 3, kk = r % 3;
        ws[WOFF_WT2 + idx] = c0w2[(co * 256 + ci) * 3 + kk];
        return;
    }
    idx -= 196608;
    if (idx < 196608) {
        int co = idx & 255, r = idx >> 8, ci = r / 3, kk = r % 3;
        ws[WOFF_WT3 + idx] = c1w1[(co * 256 + ci) * 3 + kk];
        return;
    }
    idx -= 196608;
    if (idx < 196608) {
        int co = idx & 255, r = idx >> 8, ci = r / 3, kk = r % 3;
        ws[WOFF_WT4 + idx] = c1w2[(co * 256 + ci) * 3 + kk];
        return;
    }
    idx -= 196608;
    if (idx < 8704) {
        int co = idx & 255, ci = idx >> 8;
        ws[WOFF_WTD + idx] = c0dw[co * CIN + ci];
    }
}

// ===========================================================================
// V5 sweeps: one residue-class partial (ci = r, r+4, ... ascending, kk asc).
// Per-output fmac chain identical to V2/V4's for that residue.
// ===========================================================================
__device__ __forceinline__ void bzero8(float (&bk)[8][4]) {
    #pragma unroll
    for (int i = 0; i < 8; ++i)
        #pragma unroll
        for (int j = 0; j < 4; ++j) bk[i][j] = 0.f;
}
__device__ __forceinline__ void badd8(float (&A)[8][4], const float (&B)[8][4]) {
    #pragma unroll
    for (int i = 0; i < 8; ++i)
        #pragma unroll
        for (int j = 0; j < 4; ++j) A[i][j] = A[i][j] + B[i][j];
}

__device__ __forceinline__ void sweep_s1(const float* xs, const float* __restrict__ WT,
                                         int r, int c0, int co0, float (&bk)[8][4]) {
    bzero8(bk);
    for (int ci = r; ci < CIN; ci += 4) {
        float rw[6];
        #pragma unroll
        for (int q = 0; q < 6; ++q) rw[q] = xs[ci * 69 + c0 + 2 + q];
        #pragma unroll
        for (int kk = 0; kk < 3; ++kk) {
            float wv[8];
            *(float4*)&wv[0] = *(const float4*)&WT[(ci * 3 + kk) * 256 + co0];
            *(float4*)&wv[4] = *(const float4*)&WT[(ci * 3 + kk) * 256 + co0 + 4];
            #pragma unroll
            for (int i = 0; i < 8; ++i)
                #pragma unroll
                for (int j = 0; j < 4; ++j)
                    bk[i][j] += wv[i] * rw[j + kk];
        }
    }
}

template <int DIL>
__device__ __forceinline__ void sweep_cv(const float* bufH, const float* __restrict__ WT,
                                         int r, int c0, int cL, int co0, float (&bk)[8][4]) {
    bzero8(bk);
    for (int ci = r; ci < 256; ci += 4) {
        float rw[8];
        *(float4*)&rw[0] = lds_read4(bufH, ci, cL);
        *(float4*)&rw[4] = lds_read4(bufH, ci, c0);
        #pragma unroll
        for (int kk = 0; kk < 3; ++kk) {
            float wv[8];
            *(float4*)&wv[0] = *(const float4*)&WT[(ci * 3 + kk) * 256 + co0];
            *(float4*)&wv[4] = *(const float4*)&WT[(ci * 3 + kk) * 256 + co0 + 4];
            const int off = (DIL == 2) ? 2 * kk : kk + 2;
            #pragma unroll
            for (int i = 0; i < 8; ++i)
                #pragma unroll
                for (int j = 0; j < 4; ++j)
                    bk[i][j] += wv[i] * rw[j + off];
        }
    }
}

__device__ __forceinline__ void sweep_ds(const float* xs, const float* __restrict__ WTD,
                                         int r, int c0, int co0, float (&bk)[8][4]) {
    bzero8(bk);
    for (int ci = r; ci < CIN; ci += 4) {
        float xv[4];
        #pragma unroll
        for (int q = 0; q < 4; ++q) xv[q] = xs[ci * 69 + c0 + 4 + q];
        float wv[8];
        *(float4*)&wv[0] = *(const float4*)&WTD[ci * 256 + co0];
        *(float4*)&wv[4] = *(const float4*)&WTD[ci * 256 + co0 + 4];
        #pragma unroll
        for (int i = 0; i < 8; ++i)
            #pragma unroll
            for (int j = 0; j < 4; ++j)
                bk[i][j] += wv[i] * xv[j];
    }
}

__global__ __launch_bounds__(512, 4) void tcn_v5(
    const float* __restrict__ x,  const float* __restrict__ ws,
    const float* __restrict__ c0b1, const float* __restrict__ c0g1,
    const float* __restrict__ c0bt1, const float* __restrict__ c0m1, const float* __restrict__ c0v1,
    const float* __restrict__ c0b2, const float* __restrict__ c0g2,
    const float* __restrict__ c0bt2, const float* __restrict__ c0m2, const float* __restrict__ c0v2,
    const float* __restrict__ c1b1, const float* __restrict__ c1g1,
    const float* __restrict__ c1bt1, const float* __restrict__ c1m1, const float* __restrict__ c1v1,
    const float* __restrict__ c1b2, const float* __restrict__ c1g2,
    const float* __restrict__ c1bt2, const float* __restrict__ c1m2, const float* __restrict__ c1v2,
    const float* __restrict__ c0db,
    const float* __restrict__ aw, const float* __restrict__ ab,
    const float* __restrict__ lw, const float* __restrict__ lb,
    float* __restrict__ out)
{
    __shared__ float bufH[256 * TW];   // 64 KB
    __shared__ float xs[34 * 69];      // 9.2 KB; reused for head weights

    const int b   = blockIdx.y;
    const int t0  = blockIdx.x * TT;
    const int tid = threadIdx.x;
    const int CG  = tid >> 4, TG = tid & 15;
    const int co0 = CG * 8,  c0 = TG * 4;
    const int cL  = (c0 >= 4) ? c0 - 4 : 0;

    const float* WT1 = ws + WOFF_WT1;
    const float* WT2 = ws + WOFF_WT2;
    const float* WT3 = ws + WOFF_WT3;
    const float* WT4 = ws + WOFF_WT4;
    const float* WTD = ws + WOFF_WTD;

    // stage x slab: xs[ci][col'], col' 0..67 <-> t = t0-20+col'
    for (int s = tid; s < 34 * 68; s += 512) {
        int ci = s % 34, col = s / 34;
        int t = t0 - 20 + col;
        xs[ci * 69 + col] = (t >= 0 && t < T_LEN) ? x[(b * T_LEN + t) * CIN + ci] : 0.f;
    }
    __syncthreads();

    float B1[8][4], B2[8][4], hr[8][4];

    // ---- stage 1: h1 = relu(bn1(conv0_1(x)+b1)), mask t<0 -> bufH ----------
    sweep_s1(xs, WT1, 3, c0, co0, B1);
    sweep_s1(xs, WT1, 2, c0, co0, B2); badd8(B1, B2);
    sweep_s1(xs, WT1, 1, c0, co0, B2); badd8(B1, B2);
    sweep_s1(xs, WT1, 0, c0, co0, B2);
    #pragma unroll
    for (int i = 0; i < 8; ++i) {
        int co = co0 + i;
        float sc = c0g1[co] / sqrtf(c0v1[co] + EPSV);
        float bi = (c0b1[co] - c0m1[co]) * sc + c0bt1[co];
        #pragma unroll
        for (int j = 0; j < 4; ++j) {
            float s = (B1[i][j] + B2[i][j]) * sc + bi;
            float ov = fmaxf(s, 0.f);
            int t = t0 - HALO + c0 + j;
            if (t < 0) ov = 0.f;
            B1[i][j] = ov;
        }
    }
    #pragma unroll
    for (int i = 0; i < 8; ++i)
        *lds_ptr4(bufH, co0 + i, c0) = make_float4(B1[i][0], B1[i][1], B1[i][2], B1[i][3]);
    __syncthreads();

    // ---- stage 2a: h2a = relu(bn2(conv0_2(h1)+b2)), mask -> hr -------------
    sweep_cv<1>(bufH, WT2, 3, c0, cL, co0, B1);
    sweep_cv<1>(bufH, WT2, 2, c0, cL, co0, B2); badd8(B1, B2);
    sweep_cv<1>(bufH, WT2, 1, c0, cL, co0, B2); badd8(B1, B2);
    sweep_cv<1>(bufH, WT2, 0, c0, cL, co0, B2);
    #pragma unroll
    for (int i = 0; i < 8; ++i) {
        int co = co0 + i;
        float sc = c0g2[co] / sqrtf(c0v2[co] + EPSV);
        float bi = (c0b2[co] - c0m2[co]) * sc + c0bt2[co];
        #pragma unroll
        for (int j = 0; j < 4; ++j) {
            float s = (B1[i][j] + B2[i][j]) * sc + bi;
            float ov = fmaxf(s, 0.f);
            int t = t0 - HALO + c0 + j;
            if (t < 0) ov = 0.f;
            hr[i][j] = ov;
        }
    }
    // ---- stage 2b: h2 = relu(h2a + ds(x) + db), mask ------------------------
    sweep_ds(xs, WTD, 3, c0, co0, B1); badd8(hr, B1);
    sweep_ds(xs, WTD, 2, c0, co0, B1); badd8(hr, B1);
    sweep_ds(xs, WTD, 1, c0, co0, B1); badd8(hr, B1);
    sweep_ds(xs, WTD, 0, c0, co0, B1);
    #pragma unroll
    for (int i = 0; i < 8; ++i) {
        float d = c0db[co0 + i];
        #pragma unroll
        for (int j = 0; j < 4; ++j) {
            float s = hr[i][j] + B1[i][j] + d;
            float ov = fmaxf(s, 0.f);
            int t = t0 - HALO + c0 + j;
            if (t < 0) ov = 0.f;
            hr[i][j] = ov;                       // h2 kept in regs for stage 4
        }
    }
    __syncthreads();                             // all h1 reads complete
    #pragma unroll
    for (int i = 0; i < 8; ++i)
        *lds_ptr4(bufH, co0 + i, c0) = make_float4(hr[i][0], hr[i][1], hr[i][2], hr[i][3]);
    __syncthreads();

    // ---- stage 3: h3 = relu(bn1(conv1_1(h2)+b1)) d=2, mask ------------------
    sweep_cv<2>(bufH, WT3, 3, c0, cL, co0, B1);
    sweep_cv<2>(bufH, WT3, 2, c0, cL, co0, B2); badd8(B1, B2);
    sweep_cv<2>(bufH, WT3, 1, c0, cL, co0, B2); badd8(B1, B2);
    sweep_cv<2>(bufH, WT3, 0, c0, cL, co0, B2);
    #pragma unroll
    for (int i = 0; i < 8; ++i) {
        int co = co0 + i;
        float sc = c1g1[co] / sqrtf(c1v1[co] + EPSV);
        float bi = (c1b1[co] - c1m1[co]) * sc + c1bt1[co];
        #pragma unroll
        for (int j = 0; j < 4; ++j) {
            float s = (B1[i][j] + B2[i][j]) * sc + bi;
            float ov = fmaxf(s, 0.f);
            int t = t0 - HALO + c0 + j;
            if (t < 0) ov = 0.f;
            B1[i][j] = ov;
        }
    }
    __syncthreads();                             // all h2 reads complete
    #pragma unroll
    for (int i = 0; i < 8; ++i)
        *lds_ptr4(bufH, co0 + i, c0) = make_float4(B1[i][0], B1[i][1], B1[i][2], B1[i][3]);
    __syncthreads();

    // ---- stage 4: z = relu( masked_relu(bn2(conv1_2(h3)+b2)) + h2 ) ---------
    sweep_cv<2>(bufH, WT4, 3, c0, cL, co0, B1);
    sweep_cv<2>(bufH, WT4, 2, c0, cL, co0, B2); badd8(B1, B2);
    sweep_cv<2>(bufH, WT4, 1, c0, cL, co0, B2); badd8(B1, B2);
    sweep_cv<2>(bufH, WT4, 0, c0, cL, co0, B2);
    #pragma unroll
    for (int i = 0; i < 8; ++i) {
        int co = co0 + i;
        float sc = c1g2[co] / sqrtf(c1v2[co] + EPSV);
        float bi = (c1b2[co] - c1m2[co]) * sc + c1bt2[co];
        #pragma unroll
        for (int j = 0; j < 4; ++j) {
            float s = (B1[i][j] + B2[i][j]) * sc + bi;
            float a = fmaxf(s, 0.f);
            int t = t0 - HALO + c0 + j;
            if (t < 0) a = 0.f;
            B1[i][j] = fmaxf(a + hr[i][j], 0.f); // V2 4b: relu(bufA + bufB)
        }
    }
    __syncthreads();                             // all h3 reads complete
    #pragma unroll
    for (int i = 0; i < 8; ++i)
        *lds_ptr4(bufH, co0 + i, c0) = make_float4(B1[i][0], B1[i][1], B1[i][2], B1[i][3]);
    __syncthreads();

    // ---- head (verbatim V2/V4 arithmetic; 512 threads) ----------------------
    for (int s = tid; s < 1542; s += 512) {
        float vput;
        if (s < 256)        vput = aw[s];
        else if (s < 1536)  vput = lw[s - 256];
        else if (s == 1536) vput = ab[0];
        else                vput = lb[s - 1537];
        xs[s] = vput;
    }
    __syncthreads();
    {
        int col = tid >> 3, oct = tid & 7;
        if (col >= HALO) {
            int t = t0 - HALO + col;
            float s1 = 0.f, s5[5] = {0.f, 0.f, 0.f, 0.f, 0.f};
            for (int q = 0; q < 32; ++q) {
                int co = oct * 32 + q;
                float z = bufH[hswz(co, col)];
                s1 += z * xs[co];
                #pragma unroll
                for (int nc = 0; nc < 5; ++nc) s5[nc] += z * xs[256 + co * 5 + nc];
            }
            #pragma unroll
            for (int mm = 1; mm <= 4; mm <<= 1) {
                s1 += __shfl_xor(s1, mm, 64);
                #pragma unroll
                for (int nc = 0; nc < 5; ++nc) s5[nc] += __shfl_xor(s5[nc], mm, 64);
            }
            if (oct == 0 && t < T_LEN) {
                float at = 1.f / (1.f + expf(-(s1 + xs[1536])));
                float* dst = &out[(b * T_LEN + t) * 5];
                #pragma unroll
                for (int nc = 0; nc < 5; ++nc) dst[nc] = at * s5[nc] + xs[1537 + nc];
            }
        }
    }
}

// ---------------------------------------------------------------------------
// Postproc: softmax monotone -> decisions from logits. `processed` as floats.
// TM all-ones except [1][2],[2][0]; probs>0 so vp.sum()==0 unreachable.
__global__ __launch_bounds__(256) void postproc(
    const float* __restrict__ logits, float* __restrict__ outp)
{
    const int b = blockIdx.x;
    const int tid = threadIdx.x;
    __shared__ signed char preds[4096], alt3[4096], ax2[4096], ax0[4096],
                           proc[4096], resa[4096];

    for (int t = tid; t < T_LEN; t += 256) {
        const float* p = &logits[(b * T_LEN + t) * 5];
        float l0 = p[0], l1 = p[1], l2 = p[2], l3 = p[3], l4 = p[4];
        int am = 0; float mv = l0;
        if (l1 > mv) { am = 1; mv = l1; }
        if (l2 > mv) { am = 2; mv = l2; }
        if (l3 > mv) { am = 3; mv = l3; }
        if (l4 > mv) { am = 4; mv = l4; }
        int a3 = 0; float m3 = l0;
        if (l1 > m3) { a3 = 1; m3 = l1; }
        if (l2 > m3) { a3 = 2; m3 = l2; }
        if (l4 > m3) { a3 = 4; }
        int a2 = 0; float m2 = l0;
        if (l1 > m2) { a2 = 1; m2 = l1; }
        if (l3 > m2) { a2 = 3; m2 = l3; }
        if (l4 > m2) { a2 = 4; }
        int a0 = 1; float m0 = l1;
        if (l2 > m0) { a0 = 2; m0 = l2; }
        if (l3 > m0) { a0 = 3; m0 = l3; }
        if (l4 > m0) { a0 = 4; }
        preds[t] = (signed char)am;
        alt3[t]  = (signed char)a3;
        ax2[t]   = (signed char)a2;
        ax0[t]   = (signed char)a0;
    }
    __syncthreads();
    for (int t = tid; t < T_LEN; t += 256) {
        int s0 = t - 2 > 0 ? t - 2 : 0;
        int e0 = t + 3 < T_LEN ? t + 3 : T_LEN;
        int wsum = 0;
        for (int s = s0; s < e0; ++s) wsum += (preds[s] != 3);
        int wl = e0 - s0;
        int pd = preds[t];
        proc[t] = (pd == 3 && 2 * wsum > wl) ? alt3[t] : (signed char)pd;
    }
    __syncthreads();
    if (tid == 0) {
        int p = proc[0];
        resa[0] = (signed char)p;
        for (int t = 1; t < T_LEN; ++t) {
            int c = proc[t];
            int n = c;
            if (p == 1 && c == 2) n = ax2[t];
            else if (p == 2 && c == 0) n = ax0[t];
            resa[t] = (signed char)n;
            p = n;
        }
    }
    __syncthreads();
    for (int t = tid; t < T_LEN; t += 256) outp[b * T_LEN + t] = (float)resa[t];
}

// ---------------------------------------------------------------------------
extern "C" void kernel_launch(void* const* d_in, const int* in_sizes, int n_in,
                              void* d_out, int out_size, void* d_ws, size_t ws_size,
                              hipStream_t stream)
{
    const float* x     = (const float*)d_in[0];
    const float* c0w1  = (const float*)d_in[1];
    const float* c0b1  = (const float*)d_in[2];
    const float* c0w2  = (const float*)d_in[3];
    const float* c0b2  = (const float*)d_in[4];
    const float* c0g1  = (const float*)d_in[5];
    const float* c0bt1 = (const float*)d_in[6];
    const float* c0m1  = (const float*)d_in[7];
    const float* c0v1  = (const float*)d_in[8];
    const float* c0g2  = (const float*)d_in[9];
    const float* c0bt2 = (const float*)d_in[10];
    const float* c0m2  = (const float*)d_in[11];
    const float* c0v2  = (const float*)d_in[12];
    const float* c1w1  = (const float*)d_in[13];
    const float* c1b1  = (const float*)d_in[14];
    const float* c1w2  = (const float*)d_in[15];
    const float* c1b2  = (const float*)d_in[16];
    const float* c1g1  = (const float*)d_in[17];
    const float* c1bt1 = (const float*)d_in[18];
    const float* c1m1  = (const float*)d_in[19];
    const float* c1v1  = (const float*)d_in[20];
    const float* c1g2  = (const float*)d_in[21];
    const float* c1bt2 = (const float*)d_in[22];
    const float* c1m2  = (const float*)d_in[23];
    const float* c1v2  = (const float*)d_in[24];
    const float* c0dw  = (const float*)d_in[25];
    const float* c0db  = (const float*)d_in[26];
    const float* aw    = (const float*)d_in[27];
    const float* ab    = (const float*)d_in[28];
    const float* lw    = (const float*)d_in[29];
    const float* lb    = (const float*)d_in[30];

    float* logits = (float*)d_out;
    float* ws = (float*)d_ws;   // ws path proven: rounds 5/7 dispatched it

    prep_v3<<<2440, 256, 0, stream>>>(c0w1, c0w2, c1w1, c1w2, c0dw, ws);
    tcn_v5<<<dim3(NTILE, 32), 512, 0, stream>>>(
        x, ws,
        c0b1, c0g1, c0bt1, c0m1, c0v1,
        c0b2, c0g2, c0bt2, c0m2, c0v2,
        c1b1, c1g1, c1bt1, c1m1, c1v1,
        c1b2, c1g2, c1bt2, c1m2, c1v2,
        c0db, aw, ab, lw, lb, logits);
    postproc<<<32, 256, 0, stream>>>(logits, ((float*)d_out) + 32 * 4096 * 5);
}